// Round 1
// baseline (3169.920 us; speedup 1.0000x reference)
//
#include <hip/hip_runtime.h>
#include <math.h>

#define WINDOW 4
#define NNODES 50000
#define NEDGES 400000
#define DIM 128

#define BM 64
#define BK 32

__device__ __forceinline__ float eluf(float x) {
    return x > 0.0f ? x : expm1f(x);
}

// C[N,DIM] = A'[N,DIM] @ W[DIM,DIM], where A' = bias ? elu(A + bias[col]) : A.
// Fusing the previous hop's bias+ELU into the A-load prologue saves one full
// N*D round-trip through HBM per conv.
__global__ __launch_bounds__(256) void gemm_fused(
    const float* __restrict__ A,
    const float* __restrict__ W,
    const float* __restrict__ bias,   // nullptr -> identity prologue
    float* __restrict__ C,
    int N)
{
    __shared__ float As[BM][BK + 1];  // +1 pad: conflict-free column reads
    __shared__ float Ws[BK][DIM];
    const int t  = threadIdx.x;
    const int r0 = blockIdx.x * BM;
    const int tx = t & 15;            // 16 col-groups
    const int ty = t >> 4;            // 16 row-groups

    float acc[4][8];
    #pragma unroll
    for (int i = 0; i < 4; ++i)
        #pragma unroll
        for (int j = 0; j < 8; ++j) acc[i][j] = 0.0f;

    for (int kc = 0; kc < DIM; kc += BK) {
        // Stage A tile: 64x32 floats = 512 float4, 2 per thread (coalesced 128B/row)
        #pragma unroll
        for (int l = 0; l < 2; ++l) {
            int idx = t + l * 256;
            int row = idx >> 3;
            int c4  = (idx & 7) << 2;
            int gr  = r0 + row;
            float4 v = make_float4(0.f, 0.f, 0.f, 0.f);
            if (gr < N) v = *(const float4*)(A + (size_t)gr * DIM + kc + c4);
            if (bias) {
                v.x = eluf(v.x + bias[kc + c4 + 0]);
                v.y = eluf(v.y + bias[kc + c4 + 1]);
                v.z = eluf(v.z + bias[kc + c4 + 2]);
                v.w = eluf(v.w + bias[kc + c4 + 3]);
            }
            As[row][c4 + 0] = v.x;
            As[row][c4 + 1] = v.y;
            As[row][c4 + 2] = v.z;
            As[row][c4 + 3] = v.w;
        }
        // Stage W tile: 32x128 floats = 1024 float4, 4 per thread (512B/row)
        #pragma unroll
        for (int l = 0; l < 4; ++l) {
            int idx = t + l * 256;
            int row = idx >> 5;
            int c4  = (idx & 31) << 2;
            *(float4*)&Ws[row][c4] = *(const float4*)(W + (size_t)(kc + row) * DIM + c4);
        }
        __syncthreads();
        #pragma unroll
        for (int k = 0; k < BK; ++k) {
            float av[4];
            #pragma unroll
            for (int i = 0; i < 4; ++i) av[i] = As[ty + 16 * i][k];
            // cols tx*4..tx*4+3 and 64+tx*4..: 2-way bank aliasing only (free)
            const float4 w0 = *(const float4*)&Ws[k][tx * 4];
            const float4 w1 = *(const float4*)&Ws[k][64 + tx * 4];
            #pragma unroll
            for (int i = 0; i < 4; ++i) {
                acc[i][0] += av[i] * w0.x;
                acc[i][1] += av[i] * w0.y;
                acc[i][2] += av[i] * w0.z;
                acc[i][3] += av[i] * w0.w;
                acc[i][4] += av[i] * w1.x;
                acc[i][5] += av[i] * w1.y;
                acc[i][6] += av[i] * w1.z;
                acc[i][7] += av[i] * w1.w;
            }
        }
        __syncthreads();
    }
    #pragma unroll
    for (int i = 0; i < 4; ++i) {
        int gr = r0 + ty + 16 * i;
        if (gr < N) {
            float* o = C + (size_t)gr * DIM;
            *(float4*)(o + tx * 4)      = make_float4(acc[i][0], acc[i][1], acc[i][2], acc[i][3]);
            *(float4*)(o + 64 + tx * 4) = make_float4(acc[i][4], acc[i][5], acc[i][6], acc[i][7]);
        }
    }
}

// One wave per edge: lane l handles dims 2l, 2l+1. agg[dst] += ew[e] * h[src].
__global__ __launch_bounds__(256) void scatter_add(
    const float* __restrict__ h,
    const int*   __restrict__ ei,   // [2, E] slice for this window
    const float* __restrict__ ew,
    float*       __restrict__ agg,
    int E)
{
    int gid  = blockIdx.x * blockDim.x + threadIdx.x;
    int e    = gid >> 6;
    int lane = gid & 63;
    if (e >= E) return;
    int   src = ei[e];
    int   dst = ei[E + e];
    float w   = ew[e];
    float2 v  = *(const float2*)(h + (size_t)src * DIM + lane * 2);
    float* ar = agg + (size_t)dst * DIM + lane * 2;
    atomicAdd(ar,     v.x * w);
    atomicAdd(ar + 1, v.y * w);
}

// out = elu(out + bias[d]) in place, float4-vectorized.
__global__ __launch_bounds__(256) void bias_elu_kernel(
    float* __restrict__ out, const float* __restrict__ bias, int n)
{
    int idx = blockIdx.x * blockDim.x + threadIdx.x;
    int i   = idx * 4;
    if (i >= n) return;
    float4 v = *(float4*)(out + i);
    int d = i & (DIM - 1);
    v.x = eluf(v.x + bias[d + 0]);
    v.y = eluf(v.y + bias[d + 1]);
    v.z = eluf(v.z + bias[d + 2]);
    v.w = eluf(v.w + bias[d + 3]);
    *(float4*)(out + i) = v;
}

extern "C" void kernel_launch(void* const* d_in, const int* in_sizes, int n_in,
                              void* d_out, int out_size, void* d_ws, size_t ws_size,
                              hipStream_t stream) {
    const float* x           = (const float*)d_in[0];
    const int*   edge_index  = (const int*)  d_in[1];
    const float* edge_weight = (const float*)d_in[2];
    const float* W0          = (const float*)d_in[3];
    const float* b0          = (const float*)d_in[4];
    const float* W1          = (const float*)d_in[5];
    const float* b1          = (const float*)d_in[6];
    float*       out         = (float*)d_out;

    const int N = NNODES, E = NEDGES;
    const size_t ND = (size_t)N * DIM;

    float* ws0 = (float*)d_ws;        // hW / h2 buffer
    float* ws1 = ws0 + ND;            // agg buffer

    const int gemm_grid = (N + BM - 1) / BM;               // 782
    const int scat_grid = (E * 64 + 255) / 256;            // 100000
    const int act_grid  = ((int)(ND / 4) + 255) / 256;     // 6250

    for (int w = 0; w < WINDOW; ++w) {
        const float* xw  = x  + (size_t)w * ND;
        const int*   eiw = edge_index  + (size_t)w * 2 * E;
        const float* eww = edge_weight + (size_t)w * E;
        const float* W0w = W0 + (size_t)w * DIM * DIM;
        const float* b0w = b0 + (size_t)w * DIM;
        const float* W1w = W1 + (size_t)w * DIM * DIM;
        const float* b1w = b1 + (size_t)w * DIM;
        float*       outw = out + (size_t)w * ND;

        // hop 1: hW = x @ W0
        gemm_fused<<<gemm_grid, 256, 0, stream>>>(xw, W0w, nullptr, ws0, N);
        hipMemsetAsync(ws1, 0, ND * sizeof(float), stream);
        scatter_add<<<scat_grid, 256, 0, stream>>>(ws0, eiw, eww, ws1, E);
        // hop 2: h2 = elu(agg + b0) @ W1   (prologue-fused bias+ELU)
        gemm_fused<<<gemm_grid, 256, 0, stream>>>(ws1, W1w, b0w, ws0, N);
        hipMemsetAsync(outw, 0, ND * sizeof(float), stream);
        scatter_add<<<scat_grid, 256, 0, stream>>>(ws0, eiw, eww, outw, E);
        // epilogue: out = elu(agg2 + b1)
        bias_elu_kernel<<<act_grid, 256, 0, stream>>>(outw, b1w, (int)ND);
    }
}

// Round 2
// 1085.420 us; speedup vs baseline: 2.9205x; 2.9205x over previous
//
#include <hip/hip_runtime.h>
#include <math.h>

#define WINDOW 4
#define NNODES 50000
#define NEDGES 400000
#define DIM 128

#define BM 64
#define BK 32
#define SCAN_B 256

__device__ __forceinline__ float eluf(float x) {
    return x > 0.0f ? x : expm1f(x);
}

// ---------------- GEMM: C = A' @ W, A' = bias ? elu(A+bias) : A ----------------
__global__ __launch_bounds__(256) void gemm_fused(
    const float* __restrict__ A,
    const float* __restrict__ W,
    const float* __restrict__ bias,   // nullptr -> identity prologue
    float* __restrict__ C,
    int N)
{
    __shared__ float As[BM][BK + 1];
    __shared__ float Ws[BK][DIM];
    const int t  = threadIdx.x;
    const int r0 = blockIdx.x * BM;
    const int tx = t & 15;
    const int ty = t >> 4;

    float acc[4][8];
    #pragma unroll
    for (int i = 0; i < 4; ++i)
        #pragma unroll
        for (int j = 0; j < 8; ++j) acc[i][j] = 0.0f;

    for (int kc = 0; kc < DIM; kc += BK) {
        #pragma unroll
        for (int l = 0; l < 2; ++l) {
            int idx = t + l * 256;
            int row = idx >> 3;
            int c4  = (idx & 7) << 2;
            int gr  = r0 + row;
            float4 v = make_float4(0.f, 0.f, 0.f, 0.f);
            if (gr < N) v = *(const float4*)(A + (size_t)gr * DIM + kc + c4);
            if (bias) {
                v.x = eluf(v.x + bias[kc + c4 + 0]);
                v.y = eluf(v.y + bias[kc + c4 + 1]);
                v.z = eluf(v.z + bias[kc + c4 + 2]);
                v.w = eluf(v.w + bias[kc + c4 + 3]);
            }
            As[row][c4 + 0] = v.x;
            As[row][c4 + 1] = v.y;
            As[row][c4 + 2] = v.z;
            As[row][c4 + 3] = v.w;
        }
        #pragma unroll
        for (int l = 0; l < 4; ++l) {
            int idx = t + l * 256;
            int row = idx >> 5;
            int c4  = (idx & 31) << 2;
            *(float4*)&Ws[row][c4] = *(const float4*)(W + (size_t)(kc + row) * DIM + c4);
        }
        __syncthreads();
        #pragma unroll
        for (int k = 0; k < BK; ++k) {
            float av[4];
            #pragma unroll
            for (int i = 0; i < 4; ++i) av[i] = As[ty + 16 * i][k];
            const float4 w0 = *(const float4*)&Ws[k][tx * 4];
            const float4 w1 = *(const float4*)&Ws[k][64 + tx * 4];
            #pragma unroll
            for (int i = 0; i < 4; ++i) {
                acc[i][0] += av[i] * w0.x;
                acc[i][1] += av[i] * w0.y;
                acc[i][2] += av[i] * w0.z;
                acc[i][3] += av[i] * w0.w;
                acc[i][4] += av[i] * w1.x;
                acc[i][5] += av[i] * w1.y;
                acc[i][6] += av[i] * w1.z;
                acc[i][7] += av[i] * w1.w;
            }
        }
        __syncthreads();
    }
    #pragma unroll
    for (int i = 0; i < 4; ++i) {
        int gr = r0 + ty + 16 * i;
        if (gr < N) {
            float* o = C + (size_t)gr * DIM;
            *(float4*)(o + tx * 4)      = make_float4(acc[i][0], acc[i][1], acc[i][2], acc[i][3]);
            *(float4*)(o + 64 + tx * 4) = make_float4(acc[i][4], acc[i][5], acc[i][6], acc[i][7]);
        }
    }
}

// ---------------- CSR build: histogram -> scan -> bucket ----------------
__global__ __launch_bounds__(256) void hist_kernel(
    const int* __restrict__ dst, int* __restrict__ deg, int E)
{
    int e = blockIdx.x * blockDim.x + threadIdx.x;
    if (e < E) atomicAdd(&deg[dst[e]], 1);
}

// Inclusive scan within each 256-block; offs[i+1] = partial inclusive, bsums[b]=block total.
__global__ __launch_bounds__(SCAN_B) void scan1_kernel(
    const int* __restrict__ deg, int* __restrict__ offs, int* __restrict__ bsums, int n)
{
    __shared__ int s[SCAN_B];
    int i = blockIdx.x * SCAN_B + threadIdx.x;
    int v = (i < n) ? deg[i] : 0;
    s[threadIdx.x] = v;
    __syncthreads();
    #pragma unroll
    for (int off = 1; off < SCAN_B; off <<= 1) {
        int t = (threadIdx.x >= off) ? s[threadIdx.x - off] : 0;
        __syncthreads();
        s[threadIdx.x] += t;
        __syncthreads();
    }
    if (i < n) offs[i + 1] = s[threadIdx.x];
    if (threadIdx.x == SCAN_B - 1) bsums[blockIdx.x] = s[SCAN_B - 1];
    if (i == 0) offs[0] = 0;
}

// Single-block exclusive scan of block sums (nb <= 256).
__global__ __launch_bounds__(SCAN_B) void scan2_kernel(
    const int* __restrict__ bsums, int* __restrict__ bsums2, int nb)
{
    __shared__ int s[SCAN_B];
    int v = (threadIdx.x < nb) ? bsums[threadIdx.x] : 0;
    s[threadIdx.x] = v;
    __syncthreads();
    #pragma unroll
    for (int off = 1; off < SCAN_B; off <<= 1) {
        int t = (threadIdx.x >= off) ? s[threadIdx.x - off] : 0;
        __syncthreads();
        s[threadIdx.x] += t;
        __syncthreads();
    }
    if (threadIdx.x < nb) bsums2[threadIdx.x] = s[threadIdx.x] - v;  // exclusive
}

__global__ __launch_bounds__(SCAN_B) void scan3_kernel(
    int* __restrict__ offs, const int* __restrict__ bsums2, int n)
{
    int i = blockIdx.x * SCAN_B + threadIdx.x;
    if (i < n) offs[i + 1] += bsums2[blockIdx.x];
}

// Scatter edges into dst-sorted order. Order within a dst segment is arbitrary
// (fp add reassociation — within absmax tolerance).
__global__ __launch_bounds__(256) void bucket_kernel(
    const int* __restrict__ ei,     // [2,E]: src then dst
    const float* __restrict__ ew,
    int* __restrict__ cursor,
    int* __restrict__ src_sorted, float* __restrict__ w_sorted, int E)
{
    int e = blockIdx.x * blockDim.x + threadIdx.x;
    if (e >= E) return;
    int d   = ei[E + e];
    int pos = atomicAdd(&cursor[d], 1);
    src_sorted[pos] = ei[e];
    w_sorted[pos]   = ew[e];
}

// ---------------- Aggregation: one wave per dst node, no atomics ----------------
// out[dst] = sum_{e in csr[dst]} w[e] * h[src[e]]; optional fused elu(+bias).
__global__ __launch_bounds__(256) void gather_agg(
    const float* __restrict__ h,
    const int*   __restrict__ offs,
    const int*   __restrict__ src_sorted,
    const float* __restrict__ w_sorted,
    const float* __restrict__ bias,   // nullptr -> raw sum
    float*       __restrict__ out,
    int N)
{
    int wid  = (blockIdx.x * 256 + threadIdx.x) >> 6;  // wave id == dst node
    int lane = threadIdx.x & 63;
    if (wid >= N) return;
    int beg = offs[wid], end = offs[wid + 1];
    float2 acc = make_float2(0.f, 0.f);
    for (int e = beg; e < end; ++e) {
        int   src = src_sorted[e];
        float w   = w_sorted[e];
        float2 v  = *(const float2*)(h + (size_t)src * DIM + lane * 2);
        acc.x += v.x * w;
        acc.y += v.y * w;
    }
    if (bias) {
        acc.x = eluf(acc.x + bias[lane * 2 + 0]);
        acc.y = eluf(acc.y + bias[lane * 2 + 1]);
    }
    *(float2*)(out + (size_t)wid * DIM + lane * 2) = acc;
}

extern "C" void kernel_launch(void* const* d_in, const int* in_sizes, int n_in,
                              void* d_out, int out_size, void* d_ws, size_t ws_size,
                              hipStream_t stream) {
    const float* x           = (const float*)d_in[0];
    const int*   edge_index  = (const int*)  d_in[1];
    const float* edge_weight = (const float*)d_in[2];
    const float* W0          = (const float*)d_in[3];
    const float* b0          = (const float*)d_in[4];
    const float* W1          = (const float*)d_in[5];
    const float* b1          = (const float*)d_in[6];
    float*       out         = (float*)d_out;

    const int N = NNODES, E = NEDGES;
    const size_t ND = (size_t)N * DIM;
    const int nb_scan = (N + SCAN_B - 1) / SCAN_B;   // 196 (<= 256)

    // Workspace layout (all 4-byte elements; d_ws re-poisoned every call):
    char* p = (char*)d_ws;
    float* ws0        = (float*)p;                 p += ND * sizeof(float);        // 25.6 MB
    float* ws1        = (float*)p;                 p += ND * sizeof(float);        // 25.6 MB
    int*   deg        = (int*)p;                   p += (size_t)N * sizeof(int);
    int*   offs       = (int*)p;                   p += (size_t)(N + 1) * sizeof(int);
    int*   cursor     = (int*)p;                   p += (size_t)N * sizeof(int);
    int*   bsums      = (int*)p;                   p += SCAN_B * sizeof(int);
    int*   bsums2     = (int*)p;                   p += SCAN_B * sizeof(int);
    int*   src_sorted = (int*)p;                   p += (size_t)E * sizeof(int);
    float* w_sorted   = (float*)p;                 p += (size_t)E * sizeof(float);

    const int gemm_grid = (N + BM - 1) / BM;        // 782
    const int edge_grid = (E + 255) / 256;          // 1563
    const int agg_grid  = (N * 64 + 255) / 256;     // 12500

    for (int w = 0; w < WINDOW; ++w) {
        const float* xw  = x  + (size_t)w * ND;
        const int*   eiw = edge_index  + (size_t)w * 2 * E;
        const float* eww = edge_weight + (size_t)w * E;
        const float* W0w = W0 + (size_t)w * DIM * DIM;
        const float* b0w = b0 + (size_t)w * DIM;
        const float* W1w = W1 + (size_t)w * DIM * DIM;
        const float* b1w = b1 + (size_t)w * DIM;
        float*       outw = out + (size_t)w * ND;

        // ---- build CSR by dst (reused by both hops) ----
        hipMemsetAsync(deg, 0, (size_t)N * sizeof(int), stream);
        hist_kernel <<<edge_grid, 256, 0, stream>>>(eiw + E, deg, E);
        scan1_kernel<<<nb_scan, SCAN_B, 0, stream>>>(deg, offs, bsums, N);
        scan2_kernel<<<1, SCAN_B, 0, stream>>>(bsums, bsums2, nb_scan);
        scan3_kernel<<<nb_scan, SCAN_B, 0, stream>>>(offs, bsums2, N);
        hipMemcpyAsync(cursor, offs, (size_t)N * sizeof(int),
                       hipMemcpyDeviceToDevice, stream);
        bucket_kernel<<<edge_grid, 256, 0, stream>>>(eiw, eww, cursor,
                                                     src_sorted, w_sorted, E);

        // ---- hop 1: agg = scatter(x @ W0) ----
        gemm_fused<<<gemm_grid, 256, 0, stream>>>(xw, W0w, nullptr, ws0, N);
        gather_agg<<<agg_grid, 256, 0, stream>>>(ws0, offs, src_sorted, w_sorted,
                                                 nullptr, ws1, N);
        // ---- hop 2: out = elu(scatter(elu(agg+b0) @ W1) + b1) ----
        gemm_fused<<<gemm_grid, 256, 0, stream>>>(ws1, W1w, b0w, ws0, N);
        gather_agg<<<agg_grid, 256, 0, stream>>>(ws0, offs, src_sorted, w_sorted,
                                                 b1w, outw, N);
    }
}

// Round 4
// 776.199 us; speedup vs baseline: 4.0839x; 1.3984x over previous
//
#include <hip/hip_runtime.h>
#include <hip/hip_bf16.h>
#include <math.h>

#define WINDOW 4
#define NNODES 50000
#define NEDGES 400000
#define DIM 128

#define BM 64
#define SCAN_B 256

typedef short bf16x8 __attribute__((ext_vector_type(8)));
typedef float f32x4  __attribute__((ext_vector_type(4)));

__device__ __forceinline__ float eluf(float x) {
    return x > 0.0f ? x : expm1f(x);
}
__device__ __forceinline__ float bf16_lo(unsigned int v) {
    return __uint_as_float(v << 16);
}
__device__ __forceinline__ float bf16_hi(unsigned int v) {
    return __uint_as_float(v & 0xffff0000u);
}
__device__ __forceinline__ unsigned short f2bf(float f) {
    __hip_bfloat16 h = __float2bfloat16(f);   // RNE
    return *(unsigned short*)&h;
}

// ---------- W^T cast: Wt[n*128+k] = bf16(W[k*128+n]), once per window ----------
__global__ __launch_bounds__(256) void transpose_cast_w(
    const float* __restrict__ W, unsigned short* __restrict__ Wt)
{
    int i = blockIdx.x * 256 + threadIdx.x;   // 16384
    int n = i >> 7, k = i & 127;
    Wt[i] = f2bf(W[k * DIM + n]);
}

// ---------- MFMA GEMM: C_bf16 = A' @ W  (A' = elu(A+bias) if bias) ----------
// A is fp32 (a_bf16=0, hop1 x) or bf16 (a_bf16=1, hop2 agg). WtG is bf16 W^T [n][k].
__global__ __launch_bounds__(256) void gemm_mfma(
    const void* __restrict__ Avoid,
    const unsigned short* __restrict__ WtG,
    const float* __restrict__ bias,
    unsigned short* __restrict__ C,
    int a_bf16, int N)
{
    __shared__ unsigned short As[BM][136];    // +8 pad
    __shared__ unsigned short Bs[DIM][136];
    const int t  = threadIdx.x;
    const int r0 = blockIdx.x * BM;

    if (a_bf16) {
        const unsigned short* A = (const unsigned short*)Avoid;
        #pragma unroll
        for (int l = 0; l < 4; ++l) {
            int idx = t + l * 256;            // 1024 uint4 chunks = 64x128 bf16
            int row = idx >> 4, c8 = (idx & 15) << 3;
            int gr  = r0 + row;
            uint4 v = make_uint4(0, 0, 0, 0);
            if (gr < N) v = *(const uint4*)(A + (size_t)gr * DIM + c8);
            union { uint4 u; unsigned short s[8]; } in;
            union { uint4 u; unsigned short s[8]; } ot;
            in.u = v;
            #pragma unroll
            for (int j = 0; j < 8; ++j) {
                float f = __uint_as_float((unsigned int)in.s[j] << 16);
                ot.s[j] = f2bf(eluf(f + bias[c8 + j]));
            }
            *(uint4*)&As[row][c8] = ot.u;
        }
    } else {
        const float* A = (const float*)Avoid;
        #pragma unroll
        for (int l = 0; l < 8; ++l) {
            int idx = t + l * 256;            // 2048 float4 = 64x128 fp32
            int row = idx >> 5, c4 = (idx & 31) << 2;
            int gr  = r0 + row;
            float4 v = make_float4(0.f, 0.f, 0.f, 0.f);
            if (gr < N) v = *(const float4*)(A + (size_t)gr * DIM + c4);
            union { uint2 u; unsigned short s[4]; } ot;
            ot.s[0] = f2bf(v.x); ot.s[1] = f2bf(v.y);
            ot.s[2] = f2bf(v.z); ot.s[3] = f2bf(v.w);
            *(uint2*)&As[row][c4] = ot.u;
        }
    }
    // Stage full W^T: 128x128 bf16 = 2048 uint4 chunks -> l<8 (bug in r3: l<4
    // staged only rows 0..63; rows 64..127 were uninitialized LDS -> NaN).
    #pragma unroll
    for (int l = 0; l < 8; ++l) {
        int idx = t + l * 256;                // 0..2047
        int n = idx >> 4, k8 = (idx & 15) << 3;
        *(uint4*)&Bs[n][k8] = *(const uint4*)(WtG + (size_t)n * DIM + k8);
    }
    __syncthreads();

    const int lane = t & 63, wv = t >> 6;
    const int mr = lane & 15, quad = lane >> 4;

    f32x4 acc[8];
    #pragma unroll
    for (int c = 0; c < 8; ++c) acc[c] = (f32x4){0.f, 0.f, 0.f, 0.f};

    const unsigned short* aptr = &As[wv * 16 + mr][quad * 8];
    #pragma unroll
    for (int kc = 0; kc < DIM; kc += 32) {
        bf16x8 a = *(const bf16x8*)(aptr + kc);
        #pragma unroll
        for (int c = 0; c < 8; ++c) {
            bf16x8 b = *(const bf16x8*)(&Bs[c * 16 + mr][quad * 8 + kc]);
            acc[c] = __builtin_amdgcn_mfma_f32_16x16x32_bf16(a, b, acc[c], 0, 0, 0);
        }
    }
    // C/D layout: col = lane&15, row = quad*4 + reg  [m89-verified]
    const int gr0 = r0 + wv * 16 + quad * 4;
    #pragma unroll
    for (int c = 0; c < 8; ++c) {
        int col = c * 16 + mr;
        #pragma unroll
        for (int r = 0; r < 4; ++r) {
            int gr = gr0 + r;
            if (gr < N) C[(size_t)gr * DIM + col] = f2bf(acc[c][r]);
        }
    }
}

// ---------------- CSR build: histogram -> scan -> bucket ----------------
__global__ __launch_bounds__(256) void hist_kernel(
    const int* __restrict__ dst, int* __restrict__ deg, int E)
{
    int e = blockIdx.x * blockDim.x + threadIdx.x;
    if (e < E) atomicAdd(&deg[dst[e]], 1);
}

__global__ __launch_bounds__(SCAN_B) void scan1_kernel(
    const int* __restrict__ deg, int* __restrict__ offs, int* __restrict__ bsums, int n)
{
    __shared__ int s[SCAN_B];
    int i = blockIdx.x * SCAN_B + threadIdx.x;
    int v = (i < n) ? deg[i] : 0;
    s[threadIdx.x] = v;
    __syncthreads();
    #pragma unroll
    for (int off = 1; off < SCAN_B; off <<= 1) {
        int tv = (threadIdx.x >= off) ? s[threadIdx.x - off] : 0;
        __syncthreads();
        s[threadIdx.x] += tv;
        __syncthreads();
    }
    if (i < n) offs[i + 1] = s[threadIdx.x];
    if (threadIdx.x == SCAN_B - 1) bsums[blockIdx.x] = s[SCAN_B - 1];
    if (i == 0) offs[0] = 0;
}

__global__ __launch_bounds__(SCAN_B) void scan2_kernel(
    const int* __restrict__ bsums, int* __restrict__ bsums2, int nb)
{
    __shared__ int s[SCAN_B];
    int v = (threadIdx.x < nb) ? bsums[threadIdx.x] : 0;
    s[threadIdx.x] = v;
    __syncthreads();
    #pragma unroll
    for (int off = 1; off < SCAN_B; off <<= 1) {
        int tv = (threadIdx.x >= off) ? s[threadIdx.x - off] : 0;
        __syncthreads();
        s[threadIdx.x] += tv;
        __syncthreads();
    }
    if (threadIdx.x < nb) bsums2[threadIdx.x] = s[threadIdx.x] - v;
}

__global__ __launch_bounds__(SCAN_B) void scan3_kernel(
    int* __restrict__ offs, const int* __restrict__ bsums2, int n)
{
    int i = blockIdx.x * SCAN_B + threadIdx.x;
    if (i < n) offs[i + 1] += bsums2[blockIdx.x];
}

__global__ __launch_bounds__(256) void bucket_kernel(
    const int* __restrict__ ei, const float* __restrict__ ew,
    int* __restrict__ cursor,
    int* __restrict__ src_sorted, float* __restrict__ w_sorted, int E)
{
    int e = blockIdx.x * blockDim.x + threadIdx.x;
    if (e >= E) return;
    int d   = ei[E + e];
    int pos = atomicAdd(&cursor[d], 1);
    src_sorted[pos] = ei[e];
    w_sorted[pos]   = ew[e];
}

// ---------- Aggregation: one wave per dst, bf16 gathers, 4-wide ILP ----------
// mode 0: out_bf16[dst] = sum (raw).  mode 1: out_f32[dst] = elu(sum + bias).
__global__ __launch_bounds__(256) void gather_agg(
    const unsigned short* __restrict__ h,
    const int*   __restrict__ offs,
    const int*   __restrict__ src_sorted,
    const float* __restrict__ w_sorted,
    const float* __restrict__ bias,
    void*        __restrict__ out,
    int mode, int N)
{
    int wid  = (blockIdx.x * 256 + threadIdx.x) >> 6;
    int lane = threadIdx.x & 63;
    if (wid >= N) return;
    int beg = offs[wid], end = offs[wid + 1];
    const int d0 = lane * 2;
    float ax = 0.f, ay = 0.f;

    int e = beg;
    for (; e + 4 <= end; e += 4) {
        int s0 = src_sorted[e],     s1 = src_sorted[e + 1];
        int s2 = src_sorted[e + 2], s3 = src_sorted[e + 3];
        float w0 = w_sorted[e],     w1 = w_sorted[e + 1];
        float w2 = w_sorted[e + 2], w3 = w_sorted[e + 3];
        unsigned int v0 = *(const unsigned int*)(h + (size_t)s0 * DIM + d0);
        unsigned int v1 = *(const unsigned int*)(h + (size_t)s1 * DIM + d0);
        unsigned int v2 = *(const unsigned int*)(h + (size_t)s2 * DIM + d0);
        unsigned int v3 = *(const unsigned int*)(h + (size_t)s3 * DIM + d0);
        ax += w0 * bf16_lo(v0); ay += w0 * bf16_hi(v0);
        ax += w1 * bf16_lo(v1); ay += w1 * bf16_hi(v1);
        ax += w2 * bf16_lo(v2); ay += w2 * bf16_hi(v2);
        ax += w3 * bf16_lo(v3); ay += w3 * bf16_hi(v3);
    }
    for (; e < end; ++e) {
        int s = src_sorted[e];
        float w = w_sorted[e];
        unsigned int v = *(const unsigned int*)(h + (size_t)s * DIM + d0);
        ax += w * bf16_lo(v); ay += w * bf16_hi(v);
    }

    if (mode == 0) {
        unsigned int pk = (unsigned int)f2bf(ax) | ((unsigned int)f2bf(ay) << 16);
        *((unsigned int*)out + (size_t)wid * (DIM / 2) + lane) = pk;
    } else {
        float2 r;
        r.x = eluf(ax + bias[d0 + 0]);
        r.y = eluf(ay + bias[d0 + 1]);
        *(float2*)((float*)out + (size_t)wid * DIM + d0) = r;
    }
}

extern "C" void kernel_launch(void* const* d_in, const int* in_sizes, int n_in,
                              void* d_out, int out_size, void* d_ws, size_t ws_size,
                              hipStream_t stream) {
    const float* x           = (const float*)d_in[0];
    const int*   edge_index  = (const int*)  d_in[1];
    const float* edge_weight = (const float*)d_in[2];
    const float* W0          = (const float*)d_in[3];
    const float* b0          = (const float*)d_in[4];
    const float* W1          = (const float*)d_in[5];
    const float* b1          = (const float*)d_in[6];
    float*       out         = (float*)d_out;

    const int N = NNODES, E = NEDGES;
    const size_t ND = (size_t)N * DIM;
    const int nb_scan = (N + SCAN_B - 1) / SCAN_B;   // 196

    char* p = (char*)d_ws;
    unsigned short* h_buf   = (unsigned short*)p;  p += ND * sizeof(unsigned short);
    unsigned short* agg_buf = (unsigned short*)p;  p += ND * sizeof(unsigned short);
    unsigned short* wt0     = (unsigned short*)p;  p += (size_t)DIM * DIM * sizeof(unsigned short);
    unsigned short* wt1     = (unsigned short*)p;  p += (size_t)DIM * DIM * sizeof(unsigned short);
    int*   deg        = (int*)p;                   p += (size_t)N * sizeof(int);
    int*   offs       = (int*)p;                   p += (size_t)(N + 1) * sizeof(int);
    int*   cursor     = (int*)p;                   p += (size_t)N * sizeof(int);
    int*   bsums      = (int*)p;                   p += SCAN_B * sizeof(int);
    int*   bsums2     = (int*)p;                   p += SCAN_B * sizeof(int);
    int*   src_sorted = (int*)p;                   p += (size_t)E * sizeof(int);
    float* w_sorted   = (float*)p;                 p += (size_t)E * sizeof(float);

    const int gemm_grid = (N + BM - 1) / BM;        // 782
    const int edge_grid = (E + 255) / 256;          // 1563
    const int agg_grid  = (N * 64 + 255) / 256;     // 12500

    for (int w = 0; w < WINDOW; ++w) {
        const float* xw  = x  + (size_t)w * ND;
        const int*   eiw = edge_index  + (size_t)w * 2 * E;
        const float* eww = edge_weight + (size_t)w * E;
        const float* W0w = W0 + (size_t)w * DIM * DIM;
        const float* b0w = b0 + (size_t)w * DIM;
        const float* W1w = W1 + (size_t)w * DIM * DIM;
        const float* b1w = b1 + (size_t)w * DIM;
        float*       outw = out + (size_t)w * ND;

        // weights -> bf16 W^T
        transpose_cast_w<<<64, 256, 0, stream>>>(W0w, wt0);
        transpose_cast_w<<<64, 256, 0, stream>>>(W1w, wt1);

        // CSR by dst (shared by both hops)
        hipMemsetAsync(deg, 0, (size_t)N * sizeof(int), stream);
        hist_kernel <<<edge_grid, 256, 0, stream>>>(eiw + E, deg, E);
        scan1_kernel<<<nb_scan, SCAN_B, 0, stream>>>(deg, offs, bsums, N);
        scan2_kernel<<<1, SCAN_B, 0, stream>>>(bsums, bsums2, nb_scan);
        scan3_kernel<<<nb_scan, SCAN_B, 0, stream>>>(offs, bsums2, N);
        hipMemcpyAsync(cursor, offs, (size_t)N * sizeof(int),
                       hipMemcpyDeviceToDevice, stream);
        bucket_kernel<<<edge_grid, 256, 0, stream>>>(eiw, eww, cursor,
                                                     src_sorted, w_sorted, E);

        // hop 1: h = x @ W0 ; agg = gather(h) (raw, bf16)
        gemm_mfma <<<gemm_grid, 256, 0, stream>>>(xw, wt0, nullptr, h_buf, 0, N);
        gather_agg<<<agg_grid, 256, 0, stream>>>(h_buf, offs, src_sorted, w_sorted,
                                                 nullptr, agg_buf, 0, N);
        // hop 2: h2 = elu(agg+b0) @ W1 ; out = elu(gather(h2) + b1) (fp32)
        gemm_mfma <<<gemm_grid, 256, 0, stream>>>(agg_buf, wt1, b0w, h_buf, 1, N);
        gather_agg<<<agg_grid, 256, 0, stream>>>(h_buf, offs, src_sorted, w_sorted,
                                                 b1w, outw, 1, N);
    }
}

// Round 5
// 736.443 us; speedup vs baseline: 4.3044x; 1.0540x over previous
//
#include <hip/hip_runtime.h>
#include <hip/hip_bf16.h>
#include <math.h>

#define WINDOW 4
#define NNODES 50000
#define NEDGES 400000
#define DIM 128
#define BM 64

typedef short bf16x8 __attribute__((ext_vector_type(8)));
typedef float f32x4  __attribute__((ext_vector_type(4)));

__device__ __forceinline__ float eluf(float x) {
    return x > 0.0f ? x : expm1f(x);
}
__device__ __forceinline__ float bf16_lo(unsigned int v) {
    return __uint_as_float(v << 16);
}
__device__ __forceinline__ float bf16_hi(unsigned int v) {
    return __uint_as_float(v & 0xffff0000u);
}
__device__ __forceinline__ unsigned short f2bf(float f) {
    __hip_bfloat16 h = __float2bfloat16(f);   // RNE
    return *(unsigned short*)&h;
}

// ---- prep: zero deg[nb][N] + cast/transpose W0,W1 -> wt[nb][2][128][128] ----
__global__ __launch_bounds__(256) void prep_kernel(
    const float* __restrict__ W0, const float* __restrict__ W1,
    unsigned short* __restrict__ wt, int* __restrict__ deg, int nb)
{
    int i = blockIdx.x * 256 + threadIdx.x;
    int ncast = nb * 2 * DIM * DIM;            // nb*32768
    if (i < ncast) {
        int w   = i >> 15;
        int rem = i & 32767;
        int m   = rem >> 14;                   // 0:W0 1:W1
        int j   = rem & 16383;
        int n   = j >> 7, k = j & 127;
        const float* Ws = (m ? W1 : W0) + (size_t)w * DIM * DIM;
        wt[i] = f2bf(Ws[k * DIM + n]);         // wt[(w*2+m)*16384 + n*128 + k]
    }
    if (i < nb * NNODES) deg[i] = 0;
}

// ---- hist: deg[w][dst]++ over all edges of the group ----
__global__ __launch_bounds__(256) void hist_kernel(
    const int* __restrict__ ei, int* __restrict__ deg)
{
    int e = blockIdx.x * 256 + threadIdx.x;
    int w = blockIdx.y;
    if (e < NEDGES)
        atomicAdd(&deg[w * NNODES + ei[(size_t)w * 2 * NEDGES + NEDGES + e]], 1);
}

// ---- fused scan: one 1024-thread block per window ----
// exclusive scan of deg -> offs[0..N] AND cursor (bucket's mutable copy).
// Replaces scan1+scan2+scan3+memcpy+memset of the per-window version.
__global__ __launch_bounds__(1024) void scan_fused(
    const int* __restrict__ deg, int* __restrict__ offs, int* __restrict__ cursor)
{
    const int w = blockIdx.x;
    const int* d = deg + (size_t)w * NNODES;
    int* o = offs   + (size_t)w * (NNODES + 1);
    int* c = cursor + (size_t)w * NNODES;
    __shared__ int s[1024];
    const int CH = (NNODES + 1023) / 1024;     // 49
    const int t = threadIdx.x;
    const int base = t * CH;
    int sum = 0;
    for (int j = 0; j < CH; ++j) {
        int i = base + j;
        if (i < NNODES) sum += d[i];
    }
    s[t] = sum;
    __syncthreads();
    for (int off = 1; off < 1024; off <<= 1) {
        int v = (t >= off) ? s[t - off] : 0;
        __syncthreads();
        s[t] += v;
        __syncthreads();
    }
    int run = s[t] - sum;                      // exclusive prefix
    for (int j = 0; j < CH; ++j) {
        int i = base + j;
        if (i < NNODES) { o[i] = run; c[i] = run; run += d[i]; }
    }
    if (t == 1023) o[NNODES] = run;            // == NEDGES
}

// ---- bucket: dst-sorted (src, weight) pairs, one 8B write per edge ----
__global__ __launch_bounds__(256) void bucket_kernel(
    const int* __restrict__ ei, const float* __restrict__ ew,
    int* __restrict__ cursor, int2* __restrict__ srcw)
{
    int e = blockIdx.x * 256 + threadIdx.x;
    int w = blockIdx.y;
    if (e >= NEDGES) return;
    const int* eiw = ei + (size_t)w * 2 * NEDGES;
    int d   = eiw[NEDGES + e];
    int pos = atomicAdd(&cursor[w * NNODES + d], 1);
    srcw[(size_t)w * NEDGES + pos] =
        make_int2(eiw[e], __float_as_int(ew[(size_t)w * NEDGES + e]));
}

// ---- MFMA GEMM (batched): C_bf16[w] = A'[w] @ W[w], A' = elu(A+bias) if bias ----
__global__ __launch_bounds__(256) void gemm_mfma(
    const void* __restrict__ Avoid, size_t a_stride,        // elements per window
    const unsigned short* __restrict__ WtG, size_t wt_stride,
    const float* __restrict__ bias,                          // null or stride DIM
    unsigned short* __restrict__ C,                          // stride N*DIM
    int a_bf16)
{
    __shared__ unsigned short As[BM][136];
    __shared__ unsigned short Bs[DIM][136];
    const int t  = threadIdx.x;
    const int r0 = blockIdx.x * BM;
    const int w  = blockIdx.y;
    const unsigned short* Wt = WtG + (size_t)w * wt_stride;
    unsigned short* Cw = C + (size_t)w * NNODES * DIM;

    if (a_bf16) {
        const unsigned short* A = (const unsigned short*)Avoid + (size_t)w * a_stride;
        const float* bs = bias + (size_t)w * DIM;
        #pragma unroll
        for (int l = 0; l < 4; ++l) {
            int idx = t + l * 256;             // 1024 uint4 = 64x128 bf16
            int row = idx >> 4, c8 = (idx & 15) << 3;
            int gr  = r0 + row;
            uint4 v = make_uint4(0, 0, 0, 0);
            if (gr < NNODES) v = *(const uint4*)(A + (size_t)gr * DIM + c8);
            union { uint4 u; unsigned short s[8]; } in, ot;
            in.u = v;
            #pragma unroll
            for (int j = 0; j < 8; ++j) {
                float f = __uint_as_float((unsigned int)in.s[j] << 16);
                ot.s[j] = f2bf(eluf(f + bs[c8 + j]));
            }
            *(uint4*)&As[row][c8] = ot.u;
        }
    } else {
        const float* A = (const float*)Avoid + (size_t)w * a_stride;
        #pragma unroll
        for (int l = 0; l < 8; ++l) {
            int idx = t + l * 256;             // 2048 float4 = 64x128 fp32
            int row = idx >> 5, c4 = (idx & 31) << 2;
            int gr  = r0 + row;
            float4 v = make_float4(0.f, 0.f, 0.f, 0.f);
            if (gr < NNODES) v = *(const float4*)(A + (size_t)gr * DIM + c4);
            union { uint2 u; unsigned short s[4]; } ot;
            ot.s[0] = f2bf(v.x); ot.s[1] = f2bf(v.y);
            ot.s[2] = f2bf(v.z); ot.s[3] = f2bf(v.w);
            *(uint2*)&As[row][c4] = ot.u;
        }
    }
    // full W^T: 128x128 bf16 = 2048 uint4 chunks
    #pragma unroll
    for (int l = 0; l < 8; ++l) {
        int idx = t + l * 256;
        int n = idx >> 4, k8 = (idx & 15) << 3;
        *(uint4*)&Bs[n][k8] = *(const uint4*)(Wt + (size_t)n * DIM + k8);
    }
    __syncthreads();

    const int lane = t & 63, wv = t >> 6;
    const int mr = lane & 15, quad = lane >> 4;

    f32x4 acc[8];
    #pragma unroll
    for (int c = 0; c < 8; ++c) acc[c] = (f32x4){0.f, 0.f, 0.f, 0.f};

    const unsigned short* aptr = &As[wv * 16 + mr][quad * 8];
    #pragma unroll
    for (int kc = 0; kc < DIM; kc += 32) {
        bf16x8 a = *(const bf16x8*)(aptr + kc);
        #pragma unroll
        for (int c = 0; c < 8; ++c) {
            bf16x8 b = *(const bf16x8*)(&Bs[c * 16 + mr][quad * 8 + kc]);
            acc[c] = __builtin_amdgcn_mfma_f32_16x16x32_bf16(a, b, acc[c], 0, 0, 0);
        }
    }
    // Epilogue: bounce C tile through LDS (reuse As) -> coalesced uint4 stores
    // instead of 32 scalar 2B global stores per lane.
    __syncthreads();
    const int lr0 = wv * 16 + quad * 4;
    #pragma unroll
    for (int c = 0; c < 8; ++c) {
        int col = c * 16 + mr;
        #pragma unroll
        for (int r = 0; r < 4; ++r)
            As[lr0 + r][col] = f2bf(acc[c][r]);   // C/D: col=lane&15, row=quad*4+r
    }
    __syncthreads();
    #pragma unroll
    for (int l = 0; l < 4; ++l) {
        int idx = t + l * 256;                 // 1024 = 64 rows x 16 chunks
        int row = idx >> 4, c8 = (idx & 15) << 3;
        int gr = r0 + row;
        if (gr < NNODES)
            *(uint4*)(Cw + (size_t)gr * DIM + c8) = *(const uint4*)&As[row][c8];
    }
}

// ---- gather_agg (batched): one wave per dst, int2 edge stream, 4-wide ILP ----
// mode 0: agg_bf16[w][dst] = sum.  mode 1: out_f32[w][dst] = elu(sum + bias).
__global__ __launch_bounds__(256) void gather_agg(
    const unsigned short* __restrict__ h,
    const int*  __restrict__ offs,
    const int2* __restrict__ srcw,
    const float* __restrict__ bias,
    void* __restrict__ outp,
    int mode)
{
    const int w = blockIdx.y;
    const unsigned short* hw = h + (size_t)w * NNODES * DIM;
    const int*  ow = offs + (size_t)w * (NNODES + 1);
    const int2* sw = srcw + (size_t)w * NEDGES;
    int wid  = (blockIdx.x * 256 + threadIdx.x) >> 6;
    int lane = threadIdx.x & 63;
    if (wid >= NNODES) return;
    int beg = ow[wid], end = ow[wid + 1];
    const int d0 = lane * 2;
    float ax = 0.f, ay = 0.f;

    int e = beg;
    for (; e + 4 <= end; e += 4) {
        int2 p0 = sw[e],     p1 = sw[e + 1];
        int2 p2 = sw[e + 2], p3 = sw[e + 3];
        unsigned int v0 = *(const unsigned int*)(hw + (size_t)p0.x * DIM + d0);
        unsigned int v1 = *(const unsigned int*)(hw + (size_t)p1.x * DIM + d0);
        unsigned int v2 = *(const unsigned int*)(hw + (size_t)p2.x * DIM + d0);
        unsigned int v3 = *(const unsigned int*)(hw + (size_t)p3.x * DIM + d0);
        float w0 = __int_as_float(p0.y), w1 = __int_as_float(p1.y);
        float w2 = __int_as_float(p2.y), w3 = __int_as_float(p3.y);
        ax += w0 * bf16_lo(v0); ay += w0 * bf16_hi(v0);
        ax += w1 * bf16_lo(v1); ay += w1 * bf16_hi(v1);
        ax += w2 * bf16_lo(v2); ay += w2 * bf16_hi(v2);
        ax += w3 * bf16_lo(v3); ay += w3 * bf16_hi(v3);
    }
    for (; e < end; ++e) {
        int2 p = sw[e];
        float wf = __int_as_float(p.y);
        unsigned int v = *(const unsigned int*)(hw + (size_t)p.x * DIM + d0);
        ax += wf * bf16_lo(v); ay += wf * bf16_hi(v);
    }

    if (mode == 0) {
        unsigned int pk = (unsigned int)f2bf(ax) | ((unsigned int)f2bf(ay) << 16);
        *((unsigned int*)outp + (size_t)w * NNODES * (DIM / 2)
                              + (size_t)wid * (DIM / 2) + lane) = pk;
    } else {
        const float* bs = bias + (size_t)w * DIM;
        float2 r;
        r.x = eluf(ax + bs[d0 + 0]);
        r.y = eluf(ay + bs[d0 + 1]);
        *(float2*)((float*)outp + (size_t)w * NNODES * DIM + (size_t)wid * DIM + d0) = r;
    }
}

extern "C" void kernel_launch(void* const* d_in, const int* in_sizes, int n_in,
                              void* d_out, int out_size, void* d_ws, size_t ws_size,
                              hipStream_t stream) {
    const float* x           = (const float*)d_in[0];
    const int*   edge_index  = (const int*)  d_in[1];
    const float* edge_weight = (const float*)d_in[2];
    const float* W0          = (const float*)d_in[3];
    const float* b0          = (const float*)d_in[4];
    const float* W1          = (const float*)d_in[5];
    const float* b1          = (const float*)d_in[6];
    float*       out         = (float*)d_out;

    const size_t ND = (size_t)NNODES * DIM;

    // Workspace need per batched-window: h + agg (bf16) + wt + srcw + deg/cursor/offs
    auto need = [&](int nb) -> size_t {
        return (size_t)nb * (ND * 2 + ND * 2 + 2 * DIM * DIM * 2
                             + (size_t)NEDGES * 8
                             + (size_t)NNODES * 4 * 2 + (size_t)(NNODES + 1) * 4);
    };
    int nb = WINDOW;
    while (nb > 1 && need(nb) > ws_size) nb >>= 1;   // 118MB -> 59MB -> 30MB

    char* p = (char*)d_ws;
    unsigned short* h_buf   = (unsigned short*)p;  p += (size_t)nb * ND * 2;
    unsigned short* agg_buf = (unsigned short*)p;  p += (size_t)nb * ND * 2;
    unsigned short* wt      = (unsigned short*)p;  p += (size_t)nb * 2 * DIM * DIM * 2;
    int2*           srcw    = (int2*)p;            p += (size_t)nb * NEDGES * 8;
    int*            deg     = (int*)p;             p += (size_t)nb * NNODES * 4;
    int*            cursor  = (int*)p;             p += (size_t)nb * NNODES * 4;
    int*            offs    = (int*)p;             p += (size_t)nb * (NNODES + 1) * 4;

    const dim3 eg((NEDGES + 255) / 256, nb);          // edge-parallel
    const dim3 gg((NNODES + BM - 1) / BM, nb);        // gemm tiles
    const dim3 ag((NNODES * 64 + 255) / 256, nb);     // one wave per dst
    const int  prep_grid = (nb * NNODES + 255) / 256; // covers casts too

    for (int w0 = 0; w0 < WINDOW; w0 += nb) {
        const float* W0g = W0 + (size_t)w0 * DIM * DIM;
        const float* W1g = W1 + (size_t)w0 * DIM * DIM;
        const int*   eig = edge_index  + (size_t)w0 * 2 * NEDGES;
        const float* ewg = edge_weight + (size_t)w0 * NEDGES;

        prep_kernel <<<prep_grid, 256, 0, stream>>>(W0g, W1g, wt, deg, nb);
        hist_kernel <<<eg, 256, 0, stream>>>(eig, deg);
        scan_fused  <<<nb, 1024, 0, stream>>>(deg, offs, cursor);
        bucket_kernel<<<eg, 256, 0, stream>>>(eig, ewg, cursor, srcw);

        // hop 1: h = x @ W0 ; agg = gather(h)
        gemm_mfma <<<gg, 256, 0, stream>>>(x + (size_t)w0 * ND, ND,
                                           wt, 2 * DIM * DIM, nullptr, h_buf, 0);
        gather_agg<<<ag, 256, 0, stream>>>(h_buf, offs, srcw, nullptr, agg_buf, 0);
        // hop 2: h = elu(agg+b0) @ W1 ; out = elu(gather(h) + b1)
        gemm_mfma <<<gg, 256, 0, stream>>>(agg_buf, ND,
                                           wt + DIM * DIM, 2 * DIM * DIM,
                                           b0 + (size_t)w0 * DIM, h_buf, 1);
        gather_agg<<<ag, 256, 0, stream>>>(h_buf, offs, srcw,
                                           b1 + (size_t)w0 * DIM,
                                           out + (size_t)w0 * ND, 1);
    }
}